// Round 7
// baseline (1326.940 us; speedup 1.0000x reference)
//
#include <hip/hip_runtime.h>
#include <hip/hip_fp16.h>
#include <math.h>

#define N_NODES 500000
#define N_EDGES 4000000
#define FDIM 10   // IN_DIM + HID
#define HID 8

// Dest space: interleaved, dest = 2*col (mi side) or 2*row+1 (mo side).
#define DSPACE (2 * N_NODES)
#define NB 512
#define BSHIFT 11
#define BMASK 2047
#define NB_USED ((DSPACE + BMASK) / 2048)   // 489

#define IN_BLOCKS ((N_NODES + 255) / 256)       // 1954
#define ROWS_PAD (IN_BLOCKS * 256)              // 500224

// packed fp16 pair
typedef _Float16 h2v __attribute__((ext_vector_type(2)));

__device__ __forceinline__ h2v u2h(unsigned x) {
    union { unsigned u; h2v h; } t; t.u = x; return t.h;
}
__device__ __forceinline__ unsigned packh2(float a, float b) {
    union { __half2 h; unsigned u; } t; t.h = __floats2half2_rn(a, b); return t.u;
}
__device__ __forceinline__ float rfl_f(float x) {
    return __int_as_float(__builtin_amdgcn_readfirstlane(__float_as_int(x)));
}

// Non-temporal scalar int load for single-use index streams.
__device__ __forceinline__ int nt_ld_i(const int* p) { return __builtin_nontemporal_load(p); }

// ---------------------------------------------------------------------------
// Fast transcendentals (hw exp2/rcp; error ~1e-6 vs threshold 1.35e-2)
// ---------------------------------------------------------------------------
__device__ __forceinline__ float fast_tanh(float x) {
    float e = __builtin_amdgcn_exp2f(x * 2.885390082f);  // exp(2x)
    return 1.0f - 2.0f * __builtin_amdgcn_rcpf(e + 1.0f);
}
__device__ __forceinline__ float fast_sigmoid(float x) {
    float e = __builtin_amdgcn_exp2f(-1.442695041f * x); // exp(-x)
    return __builtin_amdgcn_rcpf(1.0f + e);
}

// Edge MLP second half: acc = base + W_other^T * other_row; return sigmoid(e2).
// wq points at the 10 packed-h2 uint4 rows for the OTHER half of e1_w.
__device__ __forceinline__ float edge_sig(const uint4* __restrict__ wq,
                                          const float* base,
                                          const unsigned* cp,
                                          const float* sv, float sc) {
    float acc[HID];
#pragma unroll
    for (int j = 0; j < HID; j++) acc[j] = base[j];
#pragma unroll
    for (int kk = 0; kk < 5; kk++) {
        uint4 wa = wq[2 * kk];
        uint4 wb = wq[2 * kk + 1];
        h2v a = u2h(cp[kk]);
        acc[0] = __builtin_amdgcn_fdot2(a, u2h(wa.x), acc[0], false);
        acc[1] = __builtin_amdgcn_fdot2(a, u2h(wa.y), acc[1], false);
        acc[2] = __builtin_amdgcn_fdot2(a, u2h(wa.z), acc[2], false);
        acc[3] = __builtin_amdgcn_fdot2(a, u2h(wa.w), acc[3], false);
        acc[4] = __builtin_amdgcn_fdot2(a, u2h(wb.x), acc[4], false);
        acc[5] = __builtin_amdgcn_fdot2(a, u2h(wb.y), acc[5], false);
        acc[6] = __builtin_amdgcn_fdot2(a, u2h(wb.z), acc[6], false);
        acc[7] = __builtin_amdgcn_fdot2(a, u2h(wb.w), acc[7], false);
    }
    float d = sc;
#pragma unroll
    for (int j = 0; j < HID; j++) d += fast_tanh(acc[j]) * sv[j];
    return fast_sigmoid(d);
}

// ---------------------------------------------------------------------------
// Input network: H table (fp16, 16 B rows) + static X table (fp16, 4 B rows).
// ---------------------------------------------------------------------------
__global__ __launch_bounds__(256) void input_kernel(const float* __restrict__ x,
                                                    const float* __restrict__ win_w,
                                                    const float* __restrict__ win_b,
                                                    uint4* __restrict__ xh,
                                                    unsigned* __restrict__ xs) {
    int n = blockIdx.x * 256 + threadIdx.x;   // grid covers ROWS_PAD exactly
    float x0 = 0.f, x1 = 0.f;
    if (n < N_NODES) { x0 = x[2 * n]; x1 = x[2 * n + 1]; }
    float h[HID];
#pragma unroll
    for (int j = 0; j < HID; j++)
        h[j] = fast_tanh(x0 * win_w[j] + x1 * win_w[HID + j] + win_b[j]);
    xh[n] = make_uint4(packh2(h[0], h[1]), packh2(h[2], h[3]),
                       packh2(h[4], h[5]), packh2(h[6], h[7]));
    xs[n] = packh2(x0, x1);
}

// ---------------------------------------------------------------------------
// K0: bucket histogram, LDS-staged.
// ---------------------------------------------------------------------------
__global__ void bucket_hist_kernel(const int* __restrict__ row,
                                   const int* __restrict__ col,
                                   int* __restrict__ g_cnt) {
    __shared__ int s_cnt[NB];
    int tid = threadIdx.x;
    for (int i = tid; i < NB; i += 256) s_cnt[i] = 0;
    __syncthreads();
    int base = blockIdx.x * 4096;
#pragma unroll
    for (int k = 0; k < 16; k++) {
        int e = base + k * 256 + tid;
        if (e < N_EDGES) {
            int c = nt_ld_i(col + e), r = nt_ld_i(row + e);
            atomicAdd(&s_cnt[(2 * c) >> BSHIFT], 1);
            atomicAdd(&s_cnt[(2 * r + 1) >> BSHIFT], 1);
        }
    }
    __syncthreads();
    for (int i = tid; i < NB; i += 256) {
        int v = s_cnt[i];
        if (v) atomicAdd(&g_cnt[i], v);
    }
}

// ---------------------------------------------------------------------------
// K1: exclusive scan of bucket counts.
// ---------------------------------------------------------------------------
__global__ void bucket_scan_kernel(const int* __restrict__ g_cnt,
                                   int* __restrict__ bucket_base,
                                   int* __restrict__ bucket_cur) {
    __shared__ int s[NB];
    int t = threadIdx.x;
    int c = g_cnt[t];
    s[t] = c;
    __syncthreads();
    for (int off = 1; off < NB; off <<= 1) {
        int v = (t >= off) ? s[t - off] : 0;
        __syncthreads();
        s[t] += v;
        __syncthreads();
    }
    int ex = s[t] - c;
    bucket_base[t] = ex;
    bucket_cur[t] = ex;
    if (t == NB - 1) bucket_base[NB] = s[t];
}

// ---------------------------------------------------------------------------
// K2: binning into bucket-ordered staging (LDS), coalesced flush.
// ---------------------------------------------------------------------------
__global__ void bin_kernel(const int* __restrict__ row,
                           const int* __restrict__ col,
                           int* __restrict__ bucket_cur,
                           unsigned int* __restrict__ binned) {
    __shared__ int s_cnt[NB];
    __shared__ int s_start[NB];
    __shared__ int s_cur[NB];
    __shared__ int s_gbase[NB];
    __shared__ unsigned int s_items[8192];
    __shared__ unsigned short s_ibkt[8192];

    int tid = threadIdx.x;
    if (tid < NB) s_cnt[tid] = 0;
    __syncthreads();

    int base = blockIdx.x * 4096;
    int cc[4], rr[4];
#pragma unroll
    for (int k = 0; k < 4; k++) {
        int e = base + k * 1024 + tid;
        bool ok = (e < N_EDGES);
        cc[k] = ok ? nt_ld_i(col + e) : -1;
        rr[k] = ok ? nt_ld_i(row + e) : -1;
        if (ok) {
            atomicAdd(&s_cnt[(2 * cc[k]) >> BSHIFT], 1);
            atomicAdd(&s_cnt[(2 * rr[k] + 1) >> BSHIFT], 1);
        }
    }
    __syncthreads();

    if (tid < NB) s_start[tid] = s_cnt[tid];
    __syncthreads();
    for (int off = 1; off < NB; off <<= 1) {
        int v = 0;
        if (tid < NB && tid >= off) v = s_start[tid - off];
        __syncthreads();
        if (tid < NB) s_start[tid] += v;
        __syncthreads();
    }
    if (tid < NB) {
        int ex = s_start[tid] - s_cnt[tid];
        s_start[tid] = ex;
        s_cur[tid] = ex;
    }
    __syncthreads();

#pragma unroll
    for (int k = 0; k < 4; k++) {
        if (cc[k] >= 0) {
            int d0 = 2 * cc[k];
            int b0 = d0 >> BSHIFT;
            int s0 = atomicAdd(&s_cur[b0], 1);
            s_items[s0] = ((unsigned)(d0 & BMASK) << 19) | (unsigned)rr[k];
            s_ibkt[s0] = (unsigned short)b0;
            int d1 = 2 * rr[k] + 1;
            int b1 = d1 >> BSHIFT;
            int s1 = atomicAdd(&s_cur[b1], 1);
            s_items[s1] = ((unsigned)(d1 & BMASK) << 19) | (unsigned)cc[k];
            s_ibkt[s1] = (unsigned short)b1;
        }
    }
    __syncthreads();

    if (tid < NB) s_gbase[tid] = atomicAdd(&bucket_cur[tid], s_cnt[tid]);
    __syncthreads();

    int tot = s_start[NB - 1] + s_cnt[NB - 1];
    for (int s = tid; s < tot; s += 1024) {
        int b = s_ibkt[s];
        int g = s_gbase[b] + (s - s_start[b]);
        binned[g] = s_items[s];
    }
}

// ---------------------------------------------------------------------------
// K3: CSR finalize per bucket, all fine-grained work in LDS.
// ---------------------------------------------------------------------------
__global__ void csr_kernel(const unsigned int* __restrict__ binned,
                           const int* __restrict__ bucket_base,
                           int* __restrict__ offs,
                           int* __restrict__ entries) {
    __shared__ int s_deg[2048];
    __shared__ int s_cur[2048];
    __shared__ int s_pair[1024];

    int t = threadIdx.x;
    int b = blockIdx.x;
    if (b == 0 && t == 0) offs[DSPACE] = 2 * N_EDGES;

    int ebase = bucket_base[b];
    int eend = bucket_base[b + 1];

    s_deg[t] = 0;
    s_deg[t + 1024] = 0;
    __syncthreads();

    for (int p = ebase + t; p < eend; p += 1024)
        atomicAdd(&s_deg[binned[p] >> 19], 1);
    __syncthreads();

    int d0 = s_deg[2 * t], d1 = s_deg[2 * t + 1];
    s_pair[t] = d0 + d1;
    __syncthreads();
    for (int off = 1; off < 1024; off <<= 1) {
        int v = (t >= off) ? s_pair[t - off] : 0;
        __syncthreads();
        s_pair[t] += v;
        __syncthreads();
    }
    int pex = s_pair[t] - (d0 + d1);
    s_cur[2 * t] = pex;
    s_cur[2 * t + 1] = pex + d0;

    int dest0 = b * 2048 + 2 * t;
    if (dest0 < DSPACE) offs[dest0] = ebase + pex;
    if (dest0 + 1 < DSPACE) offs[dest0 + 1] = ebase + pex + d0;
    __syncthreads();

    for (int p = ebase + t; p < eend; p += 1024) {
        unsigned int it = binned[p];
        int dl = it >> 19;
        int other = it & 0x7FFFF;
        int pos = atomicAdd(&s_cur[dl], 1);
        entries[ebase + pos] = other;
    }
}

// ---------------------------------------------------------------------------
// Fused gather + edge-MLP + node network, DUAL-WALK:
//   ONE thread per node walks its mi-list and mo-list simultaneously.
//   Both row-gathers issue at the top of each iteration and are consumed in
//   the same iteration -> 2 independent row-misses in flight per lane
//   (structural MLP=2 the compiler cannot sink). Exhausted-side iterations
//   use clamped addresses (L1-hit repeats) and e is zeroed exactly.
//   No s_mo crossing, no per-chunk syncs; node-net epilogue on all lanes.
//   e1 weights packed-h2 in LDS (b128 broadcast); scalars in SGPRs.
// ---------------------------------------------------------------------------
__global__ __launch_bounds__(256, 4) void node_kernel(
        const uint4* __restrict__ xh,
        const unsigned* __restrict__ xs,
        const int* __restrict__ offs,
        const int* __restrict__ entries,
        const float* __restrict__ e1_w,
        const float* __restrict__ e1_b,
        const float* __restrict__ e2_w,
        const float* __restrict__ e2_b,
        const float* __restrict__ n1_w,
        const float* __restrict__ n1_b,
        const float* __restrict__ n2_w,
        const float* __restrict__ n2_b,
        uint4* __restrict__ xh_next) {
    __shared__ uint4 s_e4[20];        // e1_w all 20 rows, packed h2: pair kk -> [2kk],[2kk+1]
    __shared__ float s_scal[17];      // e1b[8], e2w[8], e2b
    __shared__ float s_n1w[30 * HID];
    __shared__ float s_n1b[HID];
    __shared__ float s_n2w[HID * HID];
    __shared__ float s_n2b[HID];

    int tid = threadIdx.x;
    if (tid < 80) {
        int kk = tid >> 3, j = tid & 7;
        ((unsigned*)s_e4)[tid] = packh2(e1_w[(2 * kk) * HID + j],
                                        e1_w[(2 * kk + 1) * HID + j]);
    } else if (tid < 88) s_scal[tid - 80] = e1_b[tid - 80];
    else if (tid < 96) s_scal[tid - 80] = e2_w[tid - 88];
    else if (tid == 96) s_scal[16] = e2_b[0];
    if (tid < 240) s_n1w[tid] = n1_w[tid];
    else if (tid < 248) s_n1b[tid - 240] = n1_b[tid - 240];
    if (tid < 64) s_n2w[tid] = n2_w[tid];
    else if (tid < 72) s_n2b[tid - 64] = n2_b[tid - 64];
    __syncthreads();

    // wave-uniform scalars -> SGPRs
    float sb[HID], sv[HID];
#pragma unroll
    for (int j = 0; j < HID; j++) { sb[j] = rfl_f(s_scal[j]); sv[j] = rfl_f(s_scal[8 + j]); }
    float sc = rfl_f(s_scal[16]);

    int n = blockIdx.x * 256 + tid;     // grid covers ROWS_PAD
    bool act = n < N_NODES;

    uint4 xq = xh[n]; unsigned xx = xs[n];   // pad rows are valid (zero-x)
    unsigned xp[5] = { xq.x, xq.y, xq.z, xq.w, xx };

    // self-half dots for both sides (bias folded):
    //   us = e1b + W_top  . x[n]  (mi side: n is col)
    //   vs = e1b + W_bot  . x[n]  (mo side: n is row)
    float us[HID], vs[HID];
#pragma unroll
    for (int j = 0; j < HID; j++) { us[j] = sb[j]; vs[j] = sb[j]; }
#pragma unroll
    for (int kk = 0; kk < 5; kk++) {
        h2v a = u2h(xp[kk]);
        uint4 wa = s_e4[2 * kk],      wb = s_e4[2 * kk + 1];       // top
        uint4 wc = s_e4[10 + 2 * kk], wd = s_e4[11 + 2 * kk];      // bottom
        us[0] = __builtin_amdgcn_fdot2(a, u2h(wa.x), us[0], false);
        us[1] = __builtin_amdgcn_fdot2(a, u2h(wa.y), us[1], false);
        us[2] = __builtin_amdgcn_fdot2(a, u2h(wa.z), us[2], false);
        us[3] = __builtin_amdgcn_fdot2(a, u2h(wa.w), us[3], false);
        us[4] = __builtin_amdgcn_fdot2(a, u2h(wb.x), us[4], false);
        us[5] = __builtin_amdgcn_fdot2(a, u2h(wb.y), us[5], false);
        us[6] = __builtin_amdgcn_fdot2(a, u2h(wb.z), us[6], false);
        us[7] = __builtin_amdgcn_fdot2(a, u2h(wb.w), us[7], false);
        vs[0] = __builtin_amdgcn_fdot2(a, u2h(wc.x), vs[0], false);
        vs[1] = __builtin_amdgcn_fdot2(a, u2h(wc.y), vs[1], false);
        vs[2] = __builtin_amdgcn_fdot2(a, u2h(wc.z), vs[2], false);
        vs[3] = __builtin_amdgcn_fdot2(a, u2h(wc.w), vs[3], false);
        vs[4] = __builtin_amdgcn_fdot2(a, u2h(wd.x), vs[4], false);
        vs[5] = __builtin_amdgcn_fdot2(a, u2h(wd.y), vs[5], false);
        vs[6] = __builtin_amdgcn_fdot2(a, u2h(wd.z), vs[6], false);
        vs[7] = __builtin_amdgcn_fdot2(a, u2h(wd.w), vs[7], false);
    }

    int pa = 0, na = 0, pb = 0, nb = 0;
    if (act) {
        int o0 = nt_ld_i(offs + 2 * n);
        int o1 = nt_ld_i(offs + 2 * n + 1);
        int o2 = nt_ld_i(offs + 2 * n + 2);
        pa = o0; na = o1 - o0;           // mi list [pa, pa+na)
        pb = o1; nb = o2 - o1;           // mo list [pb, pb+nb)
    }

    float mi[FDIM], mo[FDIM];
#pragma unroll
    for (int k = 0; k < FDIM; k++) { mi[k] = 0.f; mo[k] = 0.f; }

    int len = na > nb ? na : nb;
    for (int i = 0; i < len; ++i) {
        bool va = i < na, vb = i < nb;
        // both gathers issue before either compute (MLP=2 per lane)
        int ia = pa + (va ? i : 0);
        int ib = pb + (vb ? i : 0);
        int oa = entries[ia] & 0x7FFFF;
        int ob = entries[ib] & 0x7FFFF;
        uint4 Ha = xh[oa]; unsigned Xa = xs[oa];
        uint4 Hb = xh[ob]; unsigned Xb = xs[ob];

        unsigned ca[5] = { Ha.x, Ha.y, Ha.z, Ha.w, Xa };
        float ea = edge_sig(s_e4 + 10, us, ca, sv, sc);   // mi: other=row -> bottom
        ea = va ? ea : 0.f;
#pragma unroll
        for (int kk = 0; kk < 5; kk++) {
            h2v a = u2h(ca[kk]);
            mi[2 * kk]     += ea * (float)a.x;
            mi[2 * kk + 1] += ea * (float)a.y;
        }

        unsigned cb[5] = { Hb.x, Hb.y, Hb.z, Hb.w, Xb };
        float eb = edge_sig(s_e4, vs, cb, sv, sc);        // mo: other=col -> top
        eb = vb ? eb : 0.f;
#pragma unroll
        for (int kk = 0; kk < 5; kk++) {
            h2v b = u2h(cb[kk]);
            mo[2 * kk]     += eb * (float)b.x;
            mo[2 * kk + 1] += eb * (float)b.y;
        }
    }

    if (act) {
        float xn[FDIM];
#pragma unroll
        for (int kk = 0; kk < 5; kk++) {
            h2v a = u2h(xp[kk]);
            xn[2 * kk] = (float)a.x; xn[2 * kk + 1] = (float)a.y;
        }
        float h1[HID];
#pragma unroll
        for (int j = 0; j < HID; j++) h1[j] = s_n1b[j];
#pragma unroll
        for (int k = 0; k < FDIM; k++) {
#pragma unroll
            for (int j = 0; j < HID; j++) {
                h1[j] += mi[k] * s_n1w[k * HID + j];
                h1[j] += mo[k] * s_n1w[(FDIM + k) * HID + j];
                h1[j] += xn[k] * s_n1w[(2 * FDIM + k) * HID + j];
            }
        }
#pragma unroll
        for (int j = 0; j < HID; j++) h1[j] = fast_tanh(h1[j]);

        float H[HID];
#pragma unroll
        for (int j = 0; j < HID; j++) H[j] = s_n2b[j];
#pragma unroll
        for (int k = 0; k < HID; k++) {
#pragma unroll
            for (int j = 0; j < HID; j++) H[j] += h1[k] * s_n2w[k * HID + j];
        }
        xh_next[n] = make_uint4(packh2(fast_tanh(H[0]), fast_tanh(H[1])),
                                packh2(fast_tanh(H[2]), fast_tanh(H[3])),
                                packh2(fast_tanh(H[4]), fast_tanh(H[5])),
                                packh2(fast_tanh(H[6]), fast_tanh(H[7])));
    }
}

// ---------------------------------------------------------------------------
// Final edge network -> out. Weights packed-h2 (LDS + SGPR), dots via
// v_dot2_f32_f16. Index streams non-temporal.
// ---------------------------------------------------------------------------
__global__ __launch_bounds__(256) void edge_kernel(const int* __restrict__ row,
                                                   const int* __restrict__ col,
                                                   const uint4* __restrict__ xh,
                                                   const unsigned* __restrict__ xs,
                                                   const float* __restrict__ e1_w,
                                                   const float* __restrict__ e1_b,
                                                   const float* __restrict__ e2_w,
                                                   const float* __restrict__ e2_b,
                                                   float* __restrict__ out) {
    __shared__ uint4 s_e4[20];
    __shared__ float s_scal[17];
    int tid = threadIdx.x;
    if (tid < 80) {
        int kk = tid >> 3, j = tid & 7;
        ((unsigned*)s_e4)[tid] = packh2(e1_w[(2 * kk) * HID + j],
                                        e1_w[(2 * kk + 1) * HID + j]);
    } else if (tid < 88) s_scal[tid - 80] = e1_b[tid - 80];
    else if (tid < 96) s_scal[tid - 80] = e2_w[tid - 88];
    else if (tid == 96) s_scal[16] = e2_b[0];
    __syncthreads();

    float sb[HID], sv[HID];
#pragma unroll
    for (int j = 0; j < HID; j++) { sb[j] = rfl_f(s_scal[j]); sv[j] = rfl_f(s_scal[8 + j]); }
    float sc = rfl_f(s_scal[16]);

    int i = blockIdx.x * 256 + tid;
    if (i >= N_EDGES) return;

    int r = nt_ld_i(row + i), c = nt_ld_i(col + i);
    uint4 aq = xh[c]; unsigned ax = xs[c];
    uint4 bq = xh[r]; unsigned bx = xs[r];
    unsigned ap[5] = { aq.x, aq.y, aq.z, aq.w, ax };
    unsigned bp[5] = { bq.x, bq.y, bq.z, bq.w, bx };

    float acc[HID];
#pragma unroll
    for (int j = 0; j < HID; j++) acc[j] = sb[j];
#pragma unroll
    for (int kk = 0; kk < 5; kk++) {
        uint4 wa = s_e4[2 * kk], wb = s_e4[2 * kk + 1];
        h2v a = u2h(ap[kk]);
        acc[0] = __builtin_amdgcn_fdot2(a, u2h(wa.x), acc[0], false);
        acc[1] = __builtin_amdgcn_fdot2(a, u2h(wa.y), acc[1], false);
        acc[2] = __builtin_amdgcn_fdot2(a, u2h(wa.z), acc[2], false);
        acc[3] = __builtin_amdgcn_fdot2(a, u2h(wa.w), acc[3], false);
        acc[4] = __builtin_amdgcn_fdot2(a, u2h(wb.x), acc[4], false);
        acc[5] = __builtin_amdgcn_fdot2(a, u2h(wb.y), acc[5], false);
        acc[6] = __builtin_amdgcn_fdot2(a, u2h(wb.z), acc[6], false);
        acc[7] = __builtin_amdgcn_fdot2(a, u2h(wb.w), acc[7], false);
    }
#pragma unroll
    for (int kk = 0; kk < 5; kk++) {
        uint4 wa = s_e4[10 + 2 * kk], wb = s_e4[11 + 2 * kk];
        h2v b = u2h(bp[kk]);
        acc[0] = __builtin_amdgcn_fdot2(b, u2h(wa.x), acc[0], false);
        acc[1] = __builtin_amdgcn_fdot2(b, u2h(wa.y), acc[1], false);
        acc[2] = __builtin_amdgcn_fdot2(b, u2h(wa.z), acc[2], false);
        acc[3] = __builtin_amdgcn_fdot2(b, u2h(wa.w), acc[3], false);
        acc[4] = __builtin_amdgcn_fdot2(b, u2h(wb.x), acc[4], false);
        acc[5] = __builtin_amdgcn_fdot2(b, u2h(wb.y), acc[5], false);
        acc[6] = __builtin_amdgcn_fdot2(b, u2h(wb.z), acc[6], false);
        acc[7] = __builtin_amdgcn_fdot2(b, u2h(wb.w), acc[7], false);
    }

    float d = sc;
#pragma unroll
    for (int j = 0; j < HID; j++) d += fast_tanh(acc[j]) * sv[j];
    out[i] = fast_sigmoid(d);
}

// ---------------------------------------------------------------------------
extern "C" void kernel_launch(void* const* d_in, const int* in_sizes, int n_in,
                              void* d_out, int out_size, void* d_ws, size_t ws_size,
                              hipStream_t stream) {
    const float* x      = (const float*)d_in[0];
    const int*   eidx   = (const int*)d_in[1];
    const float* win_w  = (const float*)d_in[2];
    const float* win_b  = (const float*)d_in[3];
    const float* e1_w   = (const float*)d_in[4];
    const float* e1_b   = (const float*)d_in[5];
    const float* e2_w   = (const float*)d_in[6];
    const float* e2_b   = (const float*)d_in[7];
    const float* n1_w   = (const float*)d_in[8];
    const float* n1_b   = (const float*)d_in[9];
    const float* n2_w   = (const float*)d_in[10];
    const float* n2_b   = (const float*)d_in[11];
    float* out = (float*)d_out;

    const int* row = eidx;
    const int* col = eidx + N_EDGES;

    // Workspace layout (~90 MB); entries has +64 int pad (clamped-read safety).
    char* w = (char*)d_ws;
    uint4* xh0 = (uint4*)w;            w += (size_t)ROWS_PAD * 16;   // 8 MB
    uint4* xh1 = (uint4*)w;            w += (size_t)ROWS_PAD * 16;   // 8 MB
    unsigned* xs = (unsigned*)w;       w += (size_t)ROWS_PAD * 4;    // 2 MB
    unsigned int* binned = (unsigned int*)w; w += (size_t)2 * N_EDGES * 4;       // 32 MB
    int* entries = (int*)w;            w += ((size_t)2 * N_EDGES + 64) * 4;      // 32 MB
    int* offs = (int*)w;               w += (size_t)(DSPACE + 64) * 4;
    int* g_cnt = (int*)w;              w += NB * 4;
    int* bucket_base = (int*)w;        w += (NB + 64) * 4;
    int* bucket_cur = (int*)w;

    const int BLK = 256;
    int edge_blocks = (N_EDGES + BLK - 1) / BLK;
    int chunk_blocks = (N_EDGES + 4095) / 4096;

    // --- CSR build ---
    hipMemsetAsync(g_cnt, 0, NB * sizeof(int), stream);
    bucket_hist_kernel<<<chunk_blocks, 256, 0, stream>>>(row, col, g_cnt);
    bucket_scan_kernel<<<1, NB, 0, stream>>>(g_cnt, bucket_base, bucket_cur);
    bin_kernel<<<chunk_blocks, 1024, 0, stream>>>(row, col, bucket_cur, binned);
    csr_kernel<<<NB_USED, 1024, 0, stream>>>(binned, bucket_base, offs, entries);

    // --- input network ---
    input_kernel<<<IN_BLOCKS, BLK, 0, stream>>>(x, win_w, win_b, xh0, xs);

    // --- message-passing iterations (ping-pong H table) ---
    uint4* cur = xh0;
    uint4* nxt = xh1;
    for (int it = 0; it < 3; it++) {
        node_kernel<<<IN_BLOCKS, BLK, 0, stream>>>(
            cur, xs, offs, entries, e1_w, e1_b, e2_w, e2_b,
            n1_w, n1_b, n2_w, n2_b, nxt);
        uint4* t = cur; cur = nxt; nxt = t;
    }

    // --- final edge network -> out ---
    edge_kernel<<<edge_blocks, BLK, 0, stream>>>(
        row, col, cur, xs, e1_w, e1_b, e2_w, e2_b, out);
}